// Round 3
// baseline (777.392 us; speedup 1.0000x reference)
//
#include <hip/hip_runtime.h>
#include <math.h>

#define NB 512
#define NI 8192
#define CH 32

__device__ __forceinline__ float fexp2(float x) { return __builtin_amdgcn_exp2f(x); }
__device__ __forceinline__ float flog2(float x) { return __builtin_amdgcn_logf(x); }

#define L2E 1.44269504088896340736f  // log2(e)
#define LN2 0.69314718055994530942f  // ln(2)

// One item: inline lp/lq from logit, bit-exact-ordered fp32 DP chain (same as the
// R2-proven scheme), Bernoulli decision via prob = exp(p) (== sigmoid(p - log1mexp(p))).
__device__ __forceinline__ void step(float x, float u, int idx,
                                     float& S0, float& S1, int& sel) {
    // lp = min(log_sigmoid(x), -1e-7) = min(-(max(-x,0) + log1p(exp(-|x|))), -1e-7)
    float ex = fexp2(fabsf(x) * -L2E);     // exp(-|x|)
    float lx = flog2(1.0f + ex);           // log2(1+exp(-|x|))
    float mx = fmaxf(-x, 0.0f);
    float sp = fmaf(lx, LN2, mx);          // softplus(-x)
    float lp = fminf(-sp, -1e-7f);
    // lq = log(1 - exp(lp))   (branch-free; both reference branches equal this)
    float el = fexp2(lp * L2E);
    float lq = flog2(1.0f - el) * LN2;

    // ---- critical chain (order/rounding identical to R2's passing kernel) ----
    float x1 = S0 + lp;
    float x2 = S1 + lq;
    float d  = x1 - x2;                    // never NaN: x1 always finite
    float m  = fmaxf(x1, x2);
    float z  = fabsf(d) * -L2E;
    float e  = fexp2(z);                   // exp2(-inf)=0 handles S1=-inf start
    float a  = 1.0f + e;
    float l  = flog2(a);
    S1 = fmaf(l, LN2, m);                  // logaddexp(x1,x2)
    S0 = S0 + lq;
    // ---- decision (off-chain): prob = exp(min(x1-S1, 0)) ----
    float p    = fminf(x1 - S1, 0.0f);
    float prob = fexp2(p * L2E);           // p==0 -> 1 -> always taken (u in [0,1))
    sel = (u < prob) ? idx : sel;
}

__global__ __launch_bounds__(64, 1) void fused_kernel(const float* __restrict__ logits,
                                                      const float* __restrict__ noise,
                                                      float* __restrict__ out) {
    int lane = threadIdx.x;
    int row  = blockIdx.x * 64 + lane;
    const float* xr = logits + (size_t)row * NI;
    const float* ur = noise  + (size_t)row * NI;

    float S0 = 0.0f;
    float S1 = -INFINITY;
    int   sel = 0;  // index 0 is a guaranteed success if nothing later fires

    float xA[CH], uA[CH], xB[CH], uB[CH];

    // preload chunk 0
#pragma unroll
    for (int j = 0; j < CH / 4; ++j) {
        *(float4*)&xA[4 * j] = *(const float4*)&xr[4 * j];
        *(float4*)&uA[4 * j] = *(const float4*)&ur[4 * j];
    }

    const int NCHUNK = NI / CH;  // 256 (even)
    for (int c = 0; c < NCHUNK; c += 2) {
        const int base0 = c * CH, base1 = (c + 1) * CH, base2 = (c + 2) * CH;

        // prefetch chunk c+1
#pragma unroll
        for (int j = 0; j < CH / 4; ++j) {
            *(float4*)&xB[4 * j] = *(const float4*)&xr[base1 + 4 * j];
            *(float4*)&uB[4 * j] = *(const float4*)&ur[base1 + 4 * j];
        }
        // compute chunk c
#pragma unroll
        for (int j = 0; j < CH; ++j)
            step(xA[j], uA[j], base0 + j, S0, S1, sel);

        // prefetch chunk c+2
        if (c + 2 < NCHUNK) {
#pragma unroll
            for (int j = 0; j < CH / 4; ++j) {
                *(float4*)&xA[4 * j] = *(const float4*)&xr[base2 + 4 * j];
                *(float4*)&uA[4 * j] = *(const float4*)&ur[base2 + 4 * j];
            }
        }
        // compute chunk c+1
#pragma unroll
        for (int j = 0; j < CH; ++j)
            step(xB[j], uB[j], base1 + j, S0, S1, sel);
    }

    // ---- cooperative one-hot output write: 64 rows per block, coalesced ----
    __shared__ int sel_s[64];
    sel_s[lane] = sel;
    __syncthreads();
    float4* outb = (float4*)(out + (size_t)blockIdx.x * 64 * NI);
    for (int r = 0; r < 64; ++r) {
        int s = sel_s[r];
        float4* orow = outb + (size_t)r * (NI / 4);
#pragma unroll
        for (int k = 0; k < NI / 4 / 64; ++k) {  // 32
            int g = k * 64 + lane;
            int i0 = 4 * g;
            float4 v;
            v.x = (i0     == s) ? 1.0f : 0.0f;
            v.y = (i0 + 1 == s) ? 1.0f : 0.0f;
            v.z = (i0 + 2 == s) ? 1.0f : 0.0f;
            v.w = (i0 + 3 == s) ? 1.0f : 0.0f;
            orow[g] = v;
        }
    }
}

extern "C" void kernel_launch(void* const* d_in, const int* in_sizes, int n_in,
                              void* d_out, int out_size, void* d_ws, size_t ws_size,
                              hipStream_t stream) {
    (void)in_sizes; (void)n_in; (void)out_size; (void)d_ws; (void)ws_size;
    const float* logits = (const float*)d_in[0];
    const float* noise  = (const float*)d_in[1];
    float* out = (float*)d_out;

    fused_kernel<<<NB / 64, 64, 0, stream>>>(logits, noise, out);
}

// Round 4
// 592.634 us; speedup vs baseline: 1.3118x; 1.3118x over previous
//
#include <hip/hip_runtime.h>
#include <math.h>

#define NB 512
#define NI 8192
#define CH 16

__device__ __forceinline__ float fexp2(float x) { return __builtin_amdgcn_exp2f(x); }
__device__ __forceinline__ float flog2(float x) { return __builtin_amdgcn_logf(x); }

#define L2E 1.44269504088896340736f  // log2(e)
#define LN2 0.69314718055994530942f  // ln(2)

// ---------------- Kernel 1: parallel prep: lp, lq per item (HW trans; R3-verified) -----
__global__ __launch_bounds__(256) void prep_kernel(const float* __restrict__ logits,
                                                   float* __restrict__ Alp,   // -> ws
                                                   float* __restrict__ Blq) { // -> d_out
    int idx = blockIdx.x * blockDim.x + threadIdx.x;  // float4 group index
    float4 x4 = ((const float4*)logits)[idx];
    float4 lp4, lq4;
    const float* xs = &x4.x;
    float* lps = &lp4.x;
    float* lqs = &lq4.x;
#pragma unroll
    for (int j = 0; j < 4; ++j) {
        float x = xs[j];
        // lp = min(log_sigmoid(x), -1e-7)
        float ex = fexp2(fabsf(x) * -L2E);
        float lx = flog2(1.0f + ex);
        float mx = fmaxf(-x, 0.0f);
        float sp = fmaf(lx, LN2, mx);
        float lp = fminf(-sp, -1e-7f);
        // lq = log(1 - exp(lp))
        float el = fexp2(lp * L2E);
        float lq = flog2(1.0f - el) * LN2;
        lps[j] = lp;
        lqs[j] = lq;
    }
    ((float4*)Alp)[idx] = lp4;
    ((float4*)Blq)[idx] = lq4;
}

// ------------- Kernel 2: sequential scan + fused decision + one-hot write -------------
// Chain numerics byte-identical to the R2-passing kernel; decision byte-identical to R3.
__device__ __forceinline__ void step(float lp, float lq, float u, int idx,
                                     float& S0, float& S1, int& sel) {
    // ---- critical chain (reference rounding order) ----
    float x1 = S0 + lp;
    float x2 = S1 + lq;
    float d  = x1 - x2;                    // never NaN: x1 always finite
    float m  = fmaxf(x1, x2);
    float z  = fabsf(d) * -L2E;
    float e  = fexp2(z);                   // exp2(-inf)=0 handles S1=-inf start
    float a  = 1.0f + e;
    float l  = flog2(a);
    S1 = fmaf(l, LN2, m);                  // logaddexp(x1,x2)
    S0 = S0 + lq;
    // ---- decision (off-chain; consumes chain outputs only) ----
    float p    = fminf(x1 - S1, 0.0f);
    float prob = fexp2(p * L2E);           // p==0 -> 1 -> always taken (u in [0,1))
    sel = (u < prob) ? idx : sel;
}

__global__ __launch_bounds__(64, 1) void scan_kernel(const float* __restrict__ A,   // lp (ws)
                                                     const float* __restrict__ B,   // lq (out)
                                                     const float* __restrict__ noise,
                                                     float* __restrict__ out) {
    int lane = threadIdx.x;
    int row  = blockIdx.x * 64 + lane;
    const float* lpr = A + (size_t)row * NI;
    const float* lqr = B + (size_t)row * NI;
    const float* ur  = noise + (size_t)row * NI;

    float S0 = 0.0f;
    float S1 = -INFINITY;
    int   sel = 0;  // idx 0 is a guaranteed success if nothing later fires

    float lpA[CH], lqA[CH], uA[CH], lpB[CH], lqB[CH], uB[CH];

    // preload chunk 0
#pragma unroll
    for (int j = 0; j < CH / 4; ++j) {
        *(float4*)&lpA[4 * j] = *(const float4*)&lpr[4 * j];
        *(float4*)&lqA[4 * j] = *(const float4*)&lqr[4 * j];
        *(float4*)&uA[4 * j]  = *(const float4*)&ur[4 * j];
    }

    const int NCHUNK = NI / CH;  // 512 (even)
    for (int c = 0; c < NCHUNK; c += 2) {
        const int base0 = c * CH, base1 = (c + 1) * CH, base2 = (c + 2) * CH;

        // prefetch chunk c+1 into B buffers
#pragma unroll
        for (int j = 0; j < CH / 4; ++j) {
            *(float4*)&lpB[4 * j] = *(const float4*)&lpr[base1 + 4 * j];
            *(float4*)&lqB[4 * j] = *(const float4*)&lqr[base1 + 4 * j];
            *(float4*)&uB[4 * j]  = *(const float4*)&ur[base1 + 4 * j];
        }
        // compute chunk c
#pragma unroll
        for (int j = 0; j < CH; ++j)
            step(lpA[j], lqA[j], uA[j], base0 + j, S0, S1, sel);

        // prefetch chunk c+2 into A buffers
        if (c + 2 < NCHUNK) {
#pragma unroll
            for (int j = 0; j < CH / 4; ++j) {
                *(float4*)&lpA[4 * j] = *(const float4*)&lpr[base2 + 4 * j];
                *(float4*)&lqA[4 * j] = *(const float4*)&lqr[base2 + 4 * j];
                *(float4*)&uA[4 * j]  = *(const float4*)&ur[base2 + 4 * j];
            }
        }
        // compute chunk c+1
#pragma unroll
        for (int j = 0; j < CH; ++j)
            step(lpB[j], lqB[j], uB[j], base1 + j, S0, S1, sel);
    }

    // ---- cooperative one-hot output write: 64 rows per block, coalesced ----
    __shared__ int sel_s[64];
    sel_s[lane] = sel;
    __syncthreads();
    float4* outb = (float4*)(out + (size_t)blockIdx.x * 64 * NI);
    for (int r = 0; r < 64; ++r) {
        int s = sel_s[r];
        float4* orow = outb + (size_t)r * (NI / 4);
#pragma unroll
        for (int k = 0; k < NI / 4 / 64; ++k) {  // 32
            int g = k * 64 + lane;
            int i0 = 4 * g;
            float4 v;
            v.x = (i0     == s) ? 1.0f : 0.0f;
            v.y = (i0 + 1 == s) ? 1.0f : 0.0f;
            v.z = (i0 + 2 == s) ? 1.0f : 0.0f;
            v.w = (i0 + 3 == s) ? 1.0f : 0.0f;
            orow[g] = v;
        }
    }
}

extern "C" void kernel_launch(void* const* d_in, const int* in_sizes, int n_in,
                              void* d_out, int out_size, void* d_ws, size_t ws_size,
                              hipStream_t stream) {
    (void)in_sizes; (void)n_in; (void)out_size; (void)ws_size;
    const float* logits = (const float*)d_in[0];
    const float* noise  = (const float*)d_in[1];
    float* out = (float*)d_out;   // lq -> (read by scan) -> final 0/1 output
    float* A   = (float*)d_ws;    // lp

    int total4 = NB * NI / 4;
    prep_kernel<<<total4 / 256, 256, 0, stream>>>(logits, A, out);
    scan_kernel<<<NB / 64, 64, 0, stream>>>(A, out, noise, out);
}

// Round 5
// 582.919 us; speedup vs baseline: 1.3336x; 1.0167x over previous
//
#include <hip/hip_runtime.h>
#include <math.h>

#define NB 512
#define NI 8192
#define CH 16

__device__ __forceinline__ float fexp2(float x) { return __builtin_amdgcn_exp2f(x); }
__device__ __forceinline__ float flog2(float x) { return __builtin_amdgcn_logf(x); }

#define L2E 1.44269504088896340736f  // log2(e)
#define LN2 0.69314718055994530942f  // ln(2)

// ---------------- Kernel 1: parallel prep: lp, lq per item (HW trans; R3/R4-verified) --
__global__ __launch_bounds__(256) void prep_kernel(const float* __restrict__ logits,
                                                   float* __restrict__ Alp,   // -> ws
                                                   float* __restrict__ Blq) { // -> d_out
    int idx = blockIdx.x * blockDim.x + threadIdx.x;  // float4 group index
    float4 x4 = ((const float4*)logits)[idx];
    float4 lp4, lq4;
    const float* xs = &x4.x;
    float* lps = &lp4.x;
    float* lqs = &lq4.x;
#pragma unroll
    for (int j = 0; j < 4; ++j) {
        float x = xs[j];
        float ex = fexp2(fabsf(x) * -L2E);
        float lx = flog2(1.0f + ex);
        float mx = fmaxf(-x, 0.0f);
        float sp = fmaf(lx, LN2, mx);
        float lp = fminf(-sp, -1e-7f);
        float el = fexp2(lp * L2E);
        float lq = flog2(1.0f - el) * LN2;
        lps[j] = lp;
        lqs[j] = lq;
    }
    ((float4*)Alp)[idx] = lp4;
    ((float4*)Blq)[idx] = lq4;
}

// ------------- Kernel 2: scan + 2-step-pipelined decision + one-hot write -------------
// Chain numerics byte-identical to R2; decision formula identical to R3/R4 except the
// min(p0,0) clamp is dropped (decision-equivalent: p0>0 -> prob>1 -> success always).
// Decision fragments are placed so each lands inside a ~40-cyc trans stall window:
//   step i   : p0_i = x1 - S1            (issues in the shared S1 wait)
//   step i+1 : prob_i = fexp2(p0_i*L2E)  (inside exp window)
//   step i+2 : sel = (u_i < prob_i)?i:sel (inside exp window)
__device__ __forceinline__ void step(float lp, float lq, float u, int idx,
                                     float& S0, float& S1, int& sel,
                                     float& p0_1, float& prob_2,
                                     float& u_1, float& u_2) {
    // ---- critical chain (reference rounding order, R2-proven) ----
    float x1 = S0 + lp;
    float x2 = S1 + lq;
    float d  = x1 - x2;                    // never NaN: x1 always finite
    float m  = fmaxf(x1, x2);
    float e  = fexp2(fabsf(d) * -L2E);     // exp2(-inf)=0 handles S1=-inf start
    // ---- decision of item idx-2 (operands ready since last step) ----
    sel = (u_2 < prob_2) ? (idx - 2) : sel;
    // ---- advance item idx-1's decision: its prob (trans, in exp window) ----
    float prob_1 = fexp2(p0_1 * L2E);
    float a  = 1.0f + e;
    float l  = flog2(a);
    S1 = fmaf(l, LN2, m);                  // logaddexp(x1,x2)
    S0 = S0 + lq;
    // ---- shift pipeline; p0 of current item (shares the S1 wait with x2') ----
    prob_2 = prob_1;
    u_2 = u_1;
    u_1 = u;
    p0_1 = x1 - S1;
}

__global__ __launch_bounds__(64, 1) void scan_kernel(const float* __restrict__ A,   // lp (ws)
                                                     const float* __restrict__ B,   // lq (out)
                                                     const float* __restrict__ noise,
                                                     float* __restrict__ out) {
    int lane = threadIdx.x;
    int row  = blockIdx.x * 64 + lane;
    const float* lpr = A + (size_t)row * NI;
    const float* lqr = B + (size_t)row * NI;
    const float* ur  = noise + (size_t)row * NI;

    float S0 = 0.0f;
    float S1 = -INFINITY;
    int   sel = 0;           // item 0 is a guaranteed success
    // decision pipeline state (primed so the first two decisions are no-ops)
    float p0_1 = -INFINITY;  // -> prob 0 for phantom item -1
    float prob_2 = 0.0f;     // phantom item -2 never fires
    float u_1 = 1.0f, u_2 = 1.0f;

    float lpA[CH], lqA[CH], uA[CH], lpB[CH], lqB[CH], uB[CH];

    // preload chunk 0
#pragma unroll
    for (int j = 0; j < CH / 4; ++j) {
        *(float4*)&lpA[4 * j] = *(const float4*)&lpr[4 * j];
        *(float4*)&lqA[4 * j] = *(const float4*)&lqr[4 * j];
        *(float4*)&uA[4 * j]  = *(const float4*)&ur[4 * j];
    }

    const int NCHUNK = NI / CH;  // 512 (even)
    for (int c = 0; c < NCHUNK; c += 2) {
        const int base0 = c * CH, base1 = (c + 1) * CH, base2 = (c + 2) * CH;

        // prefetch chunk c+1 into B buffers
#pragma unroll
        for (int j = 0; j < CH / 4; ++j) {
            *(float4*)&lpB[4 * j] = *(const float4*)&lpr[base1 + 4 * j];
            *(float4*)&lqB[4 * j] = *(const float4*)&lqr[base1 + 4 * j];
            *(float4*)&uB[4 * j]  = *(const float4*)&ur[base1 + 4 * j];
        }
        // compute chunk c
#pragma unroll
        for (int j = 0; j < CH; ++j)
            step(lpA[j], lqA[j], uA[j], base0 + j, S0, S1, sel, p0_1, prob_2, u_1, u_2);

        // prefetch chunk c+2 into A buffers
        if (c + 2 < NCHUNK) {
#pragma unroll
            for (int j = 0; j < CH / 4; ++j) {
                *(float4*)&lpA[4 * j] = *(const float4*)&lpr[base2 + 4 * j];
                *(float4*)&lqA[4 * j] = *(const float4*)&lqr[base2 + 4 * j];
                *(float4*)&uA[4 * j]  = *(const float4*)&ur[base2 + 4 * j];
            }
        }
        // compute chunk c+1
#pragma unroll
        for (int j = 0; j < CH; ++j)
            step(lpB[j], lqB[j], uB[j], base1 + j, S0, S1, sel, p0_1, prob_2, u_1, u_2);
    }

    // ---- flush the 2-deep decision pipeline (items NI-2 and NI-1) ----
    sel = (u_2 < prob_2) ? (NI - 2) : sel;
    float prob_last = fexp2(p0_1 * L2E);
    sel = (u_1 < prob_last) ? (NI - 1) : sel;

    // ---- cooperative one-hot output write: 64 rows per block, coalesced ----
    __shared__ int sel_s[64];
    sel_s[lane] = sel;
    __syncthreads();
    float4* outb = (float4*)(out + (size_t)blockIdx.x * 64 * NI);
    for (int r = 0; r < 64; ++r) {
        int s = sel_s[r];
        float4* orow = outb + (size_t)r * (NI / 4);
#pragma unroll
        for (int k = 0; k < NI / 4 / 64; ++k) {  // 32
            int g = k * 64 + lane;
            int i0 = 4 * g;
            float4 v;
            v.x = (i0     == s) ? 1.0f : 0.0f;
            v.y = (i0 + 1 == s) ? 1.0f : 0.0f;
            v.z = (i0 + 2 == s) ? 1.0f : 0.0f;
            v.w = (i0 + 3 == s) ? 1.0f : 0.0f;
            orow[g] = v;
        }
    }
}

extern "C" void kernel_launch(void* const* d_in, const int* in_sizes, int n_in,
                              void* d_out, int out_size, void* d_ws, size_t ws_size,
                              hipStream_t stream) {
    (void)in_sizes; (void)n_in; (void)out_size; (void)ws_size;
    const float* logits = (const float*)d_in[0];
    const float* noise  = (const float*)d_in[1];
    float* out = (float*)d_out;   // lq -> (read by scan) -> final 0/1 output
    float* A   = (float*)d_ws;    // lp

    int total4 = NB * NI / 4;
    prep_kernel<<<total4 / 256, 256, 0, stream>>>(logits, A, out);
    scan_kernel<<<NB / 64, 64, 0, stream>>>(A, out, noise, out);
}

// Round 6
// 562.593 us; speedup vs baseline: 1.3818x; 1.0361x over previous
//
#include <hip/hip_runtime.h>
#include <math.h>

#define NB 512
#define NI 8192
#define CH 16

__device__ __forceinline__ float fexp2(float x) { return __builtin_amdgcn_exp2f(x); }
__device__ __forceinline__ float flog2(float x) { return __builtin_amdgcn_logf(x); }

#define L2E 1.44269504088896340736f  // log2(e)
#define LN2 0.69314718055994530942f  // ln(2)

// ================= PATH A (ws >= 32 MB): lu precomputed, trans-free decision ==========

__global__ __launch_bounds__(256) void prep3_kernel(const float* __restrict__ logits,
                                                    const float* __restrict__ noise,
                                                    float* __restrict__ Alp,   // ws[0:16M)
                                                    float* __restrict__ Blq,   // ws[16M:32M)
                                                    float* __restrict__ Clu) { // d_out
    int idx = blockIdx.x * blockDim.x + threadIdx.x;  // float4 group index
    float4 x4 = ((const float4*)logits)[idx];
    float4 u4 = ((const float4*)noise)[idx];
    float4 lp4, lq4, lu4;
#pragma unroll
    for (int j = 0; j < 4; ++j) {
        float x = (&x4.x)[j];
        float ex = fexp2(fabsf(x) * -L2E);
        float lx = flog2(1.0f + ex);
        float mx = fmaxf(-x, 0.0f);
        float sp = fmaf(lx, LN2, mx);
        float lp = fminf(-sp, -1e-7f);
        float el = fexp2(lp * L2E);
        float lq = flog2(1.0f - el) * LN2;
        (&lp4.x)[j] = lp;
        (&lq4.x)[j] = lq;
        // ln(u); u in [0,1). u==0 -> -inf -> always fires (matches ref: 0 < prob)
        (&lu4.x)[j] = flog2((&u4.x)[j]) * LN2;
    }
    ((float4*)Alp)[idx] = lp4;
    ((float4*)Blq)[idx] = lq4;
    ((float4*)Clu)[idx] = lu4;
}

// Chain byte-identical to R2; decision = 3 plain VALU ops pipelined one step back so
// cmp/cndmask issue inside the exp stall window (VALU-in-trans-shadow = free, R2-proven).
__device__ __forceinline__ void stepA(float lp, float lq, float lu, int idx,
                                      float& S0, float& S1, int& sel,
                                      float& p0_1, float& lu_1) {
    float x1 = S0 + lp;
    float x2 = S1 + lq;
    float d  = x1 - x2;                    // never NaN: x1 always finite
    float m  = fmaxf(x1, x2);
    float e  = fexp2(fabsf(d) * -L2E);     // exp2(-inf)=0 handles S1=-inf start
    // decision of item idx-1 (operands ready since last step; hides in exp shadow)
    sel = (lu_1 < p0_1) ? (idx - 1) : sel;
    float a  = 1.0f + e;
    float l  = flog2(a);
    S1 = fmaf(l, LN2, m);                  // logaddexp(x1,x2)
    S0 = S0 + lq;
    p0_1 = x1 - S1;                        // current item's log-prob (off-chain)
    lu_1 = lu;
}

__global__ __launch_bounds__(64, 1) void scanA_kernel(const float* __restrict__ A,   // lp
                                                      const float* __restrict__ B,   // lq
                                                      const float* __restrict__ C,   // lu (aliases out)
                                                      float* __restrict__ out) {
    int lane = threadIdx.x;
    int row  = blockIdx.x * 64 + lane;
    const float* lpr = A + (size_t)row * NI;
    const float* lqr = B + (size_t)row * NI;
    const float* lur = C + (size_t)row * NI;

    float S0 = 0.0f;
    float S1 = -INFINITY;
    int   sel = 0;           // item 0 is a guaranteed success
    float p0_1 = -INFINITY;  // phantom item -1 never fires (0 < -inf is false)
    float lu_1 = 0.0f;

    float lpA[CH], lqA[CH], luA[CH], lpB[CH], lqB[CH], luB[CH];

#pragma unroll
    for (int j = 0; j < CH / 4; ++j) {
        *(float4*)&lpA[4 * j] = *(const float4*)&lpr[4 * j];
        *(float4*)&lqA[4 * j] = *(const float4*)&lqr[4 * j];
        *(float4*)&luA[4 * j] = *(const float4*)&lur[4 * j];
    }

    const int NCHUNK = NI / CH;  // 512 (even)
    for (int c = 0; c < NCHUNK; c += 2) {
        const int base0 = c * CH, base1 = (c + 1) * CH, base2 = (c + 2) * CH;
#pragma unroll
        for (int j = 0; j < CH / 4; ++j) {
            *(float4*)&lpB[4 * j] = *(const float4*)&lpr[base1 + 4 * j];
            *(float4*)&lqB[4 * j] = *(const float4*)&lqr[base1 + 4 * j];
            *(float4*)&luB[4 * j] = *(const float4*)&lur[base1 + 4 * j];
        }
#pragma unroll
        for (int j = 0; j < CH; ++j)
            stepA(lpA[j], lqA[j], luA[j], base0 + j, S0, S1, sel, p0_1, lu_1);

        if (c + 2 < NCHUNK) {
#pragma unroll
            for (int j = 0; j < CH / 4; ++j) {
                *(float4*)&lpA[4 * j] = *(const float4*)&lpr[base2 + 4 * j];
                *(float4*)&lqA[4 * j] = *(const float4*)&lqr[base2 + 4 * j];
                *(float4*)&luA[4 * j] = *(const float4*)&lur[base2 + 4 * j];
            }
        }
#pragma unroll
        for (int j = 0; j < CH; ++j)
            stepA(lpB[j], lqB[j], luB[j], base1 + j, S0, S1, sel, p0_1, lu_1);
    }
    // flush: decision for item NI-1
    sel = (lu_1 < p0_1) ? (NI - 1) : sel;

    // cooperative one-hot output write (all lu reads of this block's rows are done)
    __shared__ int sel_s[64];
    sel_s[lane] = sel;
    __syncthreads();
    float4* outb = (float4*)(out + (size_t)blockIdx.x * 64 * NI);
    for (int r = 0; r < 64; ++r) {
        int s = sel_s[r];
        float4* orow = outb + (size_t)r * (NI / 4);
#pragma unroll
        for (int k = 0; k < NI / 4 / 64; ++k) {  // 32
            int g = k * 64 + lane;
            int i0 = 4 * g;
            float4 v;
            v.x = (i0     == s) ? 1.0f : 0.0f;
            v.y = (i0 + 1 == s) ? 1.0f : 0.0f;
            v.z = (i0 + 2 == s) ? 1.0f : 0.0f;
            v.w = (i0 + 3 == s) ? 1.0f : 0.0f;
            orow[g] = v;
        }
    }
}

// ================= PATH B (fallback, ws < 32 MB): exact R5 kernels ====================

__global__ __launch_bounds__(256) void prep_kernel(const float* __restrict__ logits,
                                                   float* __restrict__ Alp,
                                                   float* __restrict__ Blq) {
    int idx = blockIdx.x * blockDim.x + threadIdx.x;
    float4 x4 = ((const float4*)logits)[idx];
    float4 lp4, lq4;
#pragma unroll
    for (int j = 0; j < 4; ++j) {
        float x = (&x4.x)[j];
        float ex = fexp2(fabsf(x) * -L2E);
        float lx = flog2(1.0f + ex);
        float mx = fmaxf(-x, 0.0f);
        float sp = fmaf(lx, LN2, mx);
        float lp = fminf(-sp, -1e-7f);
        float el = fexp2(lp * L2E);
        float lq = flog2(1.0f - el) * LN2;
        (&lp4.x)[j] = lp;
        (&lq4.x)[j] = lq;
    }
    ((float4*)Alp)[idx] = lp4;
    ((float4*)Blq)[idx] = lq4;
}

__device__ __forceinline__ void stepB(float lp, float lq, float u, int idx,
                                      float& S0, float& S1, int& sel,
                                      float& p0_1, float& prob_2,
                                      float& u_1, float& u_2) {
    float x1 = S0 + lp;
    float x2 = S1 + lq;
    float d  = x1 - x2;
    float m  = fmaxf(x1, x2);
    float e  = fexp2(fabsf(d) * -L2E);
    sel = (u_2 < prob_2) ? (idx - 2) : sel;
    float prob_1 = fexp2(p0_1 * L2E);
    float a  = 1.0f + e;
    float l  = flog2(a);
    S1 = fmaf(l, LN2, m);
    S0 = S0 + lq;
    prob_2 = prob_1;
    u_2 = u_1;
    u_1 = u;
    p0_1 = x1 - S1;
}

__global__ __launch_bounds__(64, 1) void scanB_kernel(const float* __restrict__ A,
                                                      const float* __restrict__ B,
                                                      const float* __restrict__ noise,
                                                      float* __restrict__ out) {
    int lane = threadIdx.x;
    int row  = blockIdx.x * 64 + lane;
    const float* lpr = A + (size_t)row * NI;
    const float* lqr = B + (size_t)row * NI;
    const float* ur  = noise + (size_t)row * NI;

    float S0 = 0.0f;
    float S1 = -INFINITY;
    int   sel = 0;
    float p0_1 = -INFINITY;
    float prob_2 = 0.0f;
    float u_1 = 1.0f, u_2 = 1.0f;

    float lpA[CH], lqA[CH], uA[CH], lpB[CH], lqB[CH], uB[CH];
#pragma unroll
    for (int j = 0; j < CH / 4; ++j) {
        *(float4*)&lpA[4 * j] = *(const float4*)&lpr[4 * j];
        *(float4*)&lqA[4 * j] = *(const float4*)&lqr[4 * j];
        *(float4*)&uA[4 * j]  = *(const float4*)&ur[4 * j];
    }
    const int NCHUNK = NI / CH;
    for (int c = 0; c < NCHUNK; c += 2) {
        const int base0 = c * CH, base1 = (c + 1) * CH, base2 = (c + 2) * CH;
#pragma unroll
        for (int j = 0; j < CH / 4; ++j) {
            *(float4*)&lpB[4 * j] = *(const float4*)&lpr[base1 + 4 * j];
            *(float4*)&lqB[4 * j] = *(const float4*)&lqr[base1 + 4 * j];
            *(float4*)&uB[4 * j]  = *(const float4*)&ur[base1 + 4 * j];
        }
#pragma unroll
        for (int j = 0; j < CH; ++j)
            stepB(lpA[j], lqA[j], uA[j], base0 + j, S0, S1, sel, p0_1, prob_2, u_1, u_2);
        if (c + 2 < NCHUNK) {
#pragma unroll
            for (int j = 0; j < CH / 4; ++j) {
                *(float4*)&lpA[4 * j] = *(const float4*)&lpr[base2 + 4 * j];
                *(float4*)&lqA[4 * j] = *(const float4*)&lqr[base2 + 4 * j];
                *(float4*)&uA[4 * j]  = *(const float4*)&ur[base2 + 4 * j];
            }
        }
#pragma unroll
        for (int j = 0; j < CH; ++j)
            stepB(lpB[j], lqB[j], uB[j], base1 + j, S0, S1, sel, p0_1, prob_2, u_1, u_2);
    }
    sel = (u_2 < prob_2) ? (NI - 2) : sel;
    float prob_last = fexp2(p0_1 * L2E);
    sel = (u_1 < prob_last) ? (NI - 1) : sel;

    __shared__ int sel_s[64];
    sel_s[lane] = sel;
    __syncthreads();
    float4* outb = (float4*)(out + (size_t)blockIdx.x * 64 * NI);
    for (int r = 0; r < 64; ++r) {
        int s = sel_s[r];
        float4* orow = outb + (size_t)r * (NI / 4);
#pragma unroll
        for (int k = 0; k < NI / 4 / 64; ++k) {
            int g = k * 64 + lane;
            int i0 = 4 * g;
            float4 v;
            v.x = (i0     == s) ? 1.0f : 0.0f;
            v.y = (i0 + 1 == s) ? 1.0f : 0.0f;
            v.z = (i0 + 2 == s) ? 1.0f : 0.0f;
            v.w = (i0 + 3 == s) ? 1.0f : 0.0f;
            orow[g] = v;
        }
    }
}

extern "C" void kernel_launch(void* const* d_in, const int* in_sizes, int n_in,
                              void* d_out, int out_size, void* d_ws, size_t ws_size,
                              hipStream_t stream) {
    (void)in_sizes; (void)n_in; (void)out_size;
    const float* logits = (const float*)d_in[0];
    const float* noise  = (const float*)d_in[1];
    float* out = (float*)d_out;
    float* ws  = (float*)d_ws;

    const size_t STREAM_ELEMS = (size_t)NB * NI;          // 4,194,304
    int total4 = NB * NI / 4;

    if (ws_size >= 2 * STREAM_ELEMS * sizeof(float)) {
        // PATH A: lp,lq in ws; lu in d_out (read by scan, then overwritten by one-hot)
        float* lp = ws;
        float* lq = ws + STREAM_ELEMS;
        prep3_kernel<<<total4 / 256, 256, 0, stream>>>(logits, noise, lp, lq, out);
        scanA_kernel<<<NB / 64, 64, 0, stream>>>(lp, lq, out, out);
    } else {
        // PATH B (R5): lp in ws; lq in d_out
        prep_kernel<<<total4 / 256, 256, 0, stream>>>(logits, ws, out);
        scanB_kernel<<<NB / 64, 64, 0, stream>>>(ws, out, noise, out);
    }
}